// Round 5
// baseline (792.191 us; speedup 1.0000x reference)
//
#include <hip/hip_runtime.h>

// Problem constants
#define BATCH 4
#define CH    64
#define HH    64
#define WW    64
#define LL    4096          // HH*WW
#define SPLITS 8
#define RPS   512           // LL/SPLITS
#define BM    128           // r tile
#define BN    128           // l tile
#define NRT   (RPS/BM)      // 4

// LDS tile: per side 128 rows x 96 ushort (3 comps x 32 k), 192 B/row, 24 KB
#define RSTB  192           // row stride bytes
#define BSOFF 24576         // Bs byte offset within LDSB

// Padded pre-split global image Gp[side][b][comp][c8(8)][4356][8ch] (ushort)
#define PAD_L   4356        // 66*66
#define GP_BYTE_BASE 1376256
#define GP_SIDE_STRIDE 6690816   // 4*3*8*4356*8*2
#define GP_B_STRIDE    1672704   // 3*8*4356*8*2
#define GP_COMP_STRIDE 557568    // 8*4356*16
#define GP_TOTAL       13381632  // 2*GP_SIDE_STRIDE

// Workspace layout (float words)
#define WS_SSQ_RS 0
#define WS_SSQ_LR 16384
#define WS_INV_RS 32768
#define WS_INV_LR 49152
#define WS_PMAX   65536      // [B*SPLITS*L] = 131072
#define WS_PARG   196608     // [B*SPLITS*L] = 131072
#define WS_ARG    327680     // [B*L]

typedef __attribute__((ext_vector_type(8))) short short8b;
typedef __attribute__((ext_vector_type(4))) float f32x4;

__device__ __forceinline__ void gload16(const void* g, void* l) {
    __builtin_amdgcn_global_load_lds(
        (const __attribute__((address_space(1))) unsigned int*)g,
        (__attribute__((address_space(3))) unsigned int*)l, 16, 0, 0);
}

// -------- 0) pre-split: fp32 -> 3 truncated bf16 comps, padded image --------
__global__ void k_split(const float* __restrict__ lrsr,
                        const float* __restrict__ refsr,
                        float* __restrict__ ws) {
    int tid  = threadIdx.x;
    int pos  = blockIdx.x * 256 + tid;          // 0..4095
    int c8   = blockIdx.y;                      // 0..7
    int side = blockIdx.z >> 2;                 // 0 = refsr(A), 1 = lrsr(B)
    int b    = blockIdx.z & 3;
    const float* src = (side ? lrsr : refsr) + (size_t)b * CH * LL + c8 * 8 * LL + pos;
    int ppos = (pos >> 6) * 66 + (pos & 63) + 67;   // (y+1)*66 + (x+1)
    char* dst = (char*)ws + GP_BYTE_BASE + side * GP_SIDE_STRIDE + b * GP_B_STRIDE
              + (size_t)(c8 * PAD_L + ppos) * 16;
    union { unsigned short u[8]; uint4 v; } w0, w1, w2;
    #pragma unroll
    for (int cc = 0; cc < 8; ++cc) {
        float x = src[cc * LL];
        unsigned u0 = __float_as_uint(x);
        float f0 = __uint_as_float(u0 & 0xffff0000u);
        float r1 = x - f0;
        unsigned u1 = __float_as_uint(r1);
        float f1 = __uint_as_float(u1 & 0xffff0000u);
        float r2 = r1 - f1;
        w0.u[cc] = (unsigned short)(u0 >> 16);
        w1.u[cc] = (unsigned short)(u1 >> 16);
        w2.u[cc] = (unsigned short)(__float_as_uint(r2) >> 16);
    }
    *(uint4*)(dst)                      = w0.v;
    *(uint4*)(dst + GP_COMP_STRIDE)     = w1.v;
    *(uint4*)(dst + 2 * GP_COMP_STRIDE) = w2.v;
}

// -------- 1) channel sum-of-squares per position (both inputs) --------
__global__ void k_ssq(const float* __restrict__ lrsr,
                      const float* __restrict__ refsr,
                      float* __restrict__ ws) {
    int t = blockIdx.x * 256 + threadIdx.x;      // 0..B*L-1
    int b = t >> 12;
    int r = t & (LL - 1);
    const float* pl = lrsr + (size_t)b * CH * LL + r;
    const float* pr = refsr + (size_t)b * CH * LL + r;
    float sl = 0.f, sr = 0.f;
    #pragma unroll 8
    for (int c = 0; c < CH; ++c) {
        float a = pl[c * LL]; sl += a * a;
        float d = pr[c * LL]; sr += d * d;
    }
    ws[WS_SSQ_RS + t] = sr;
    ws[WS_SSQ_LR + t] = sl;
}

// -------- 2) 3x3 box-sum of ssq (zero pad) -> 1/max(norm,eps) --------
__global__ void k_inv(float* __restrict__ ws) {
    int t = blockIdx.x * 256 + threadIdx.x;      // 0..B*L-1
    int b = t >> 12;
    int r = t & (LL - 1);
    int y = r >> 6, x = r & 63;
    float srs = 0.f, slr = 0.f;
    for (int di = -1; di <= 1; ++di) {
        int yy = y + di;
        if ((unsigned)yy >= (unsigned)HH) continue;
        for (int dj = -1; dj <= 1; ++dj) {
            int xx = x + dj;
            if ((unsigned)xx >= (unsigned)WW) continue;
            int idx = b * LL + yy * WW + xx;
            srs += ws[WS_SSQ_RS + idx];
            slr += ws[WS_SSQ_LR + idx];
        }
    }
    ws[WS_INV_RS + t] = 1.f / fmaxf(sqrtf(srs), 1e-12f);
    ws[WS_INV_LR + t] = 1.f / fmaxf(sqrtf(slr), 1e-12f);
}

// -------- 3) MFMA corr GEMM, async global_load_lds pipelined --------
__global__ __launch_bounds__(256, 3)
void k_corrmax(float* __restrict__ ws) {
    __shared__ __align__(16) unsigned short LDSB[24576];  // As 24KB | Bs 24KB

    int tid  = threadIdx.x;
    int b    = blockIdx.z;
    int l0   = blockIdx.x * BN;
    int rbs  = blockIdx.y * RPS;

    int lane = tid & 63;
    int w    = tid >> 6;        // wave 0..3; waves 0-1 stage A, 2-3 stage B
    int wr   = w >> 1;
    int wc   = w & 1;
    int ln   = lane & 15;
    int g    = lane >> 4;

    const float* invn_rs = ws + WS_INV_RS + b * LL;
    const char* gp  = (const char*)ws + GP_BYTE_BASE + b * GP_B_STRIDE;
    const char* bp  = gp + ((w < 2) ? 0 : GP_SIDE_STRIDE);   // A=refsr, B=lrsr

    // ---- per-lane staging constants: 12 chunk-issues per wave ----
    int LC[12];     // global byte offset (lane-dependent part)
    int LB[12];     // LDS byte offset (wave-uniform)
    {
        int wm = (w & 1) * 12;              // chunk index within side region
        #pragma unroll
        for (int n = 0; n < 12; ++n) {
            int mm  = wm + n;               // 0..23 within side tile
            int G   = mm * 64 + lane;       // 16B granule index
            int row = G / 12;
            int rem = G - row * 12;
            int comp = rem >> 2;
            int sl   = rem & 3;
            int o    = sl ^ ((row >> 2) & 3);
            LC[n] = (comp * (8 * PAD_L) + o * PAD_L + row + 2 * (row >> 6)) * 16;
            LB[n] = ((w < 2) ? 0 : BSOFF) + mm * 1024;
        }
    }

    // ---- fragment LDS byte offsets ----
    int arow[4], brow[4];
    int swz = (g ^ ((ln >> 2) & 3)) << 4;
    #pragma unroll
    for (int mf = 0; mf < 4; ++mf) {
        arow[mf] = (wr * 64 + mf * 16 + ln) * RSTB + swz;
        brow[mf] = BSOFF + (wc * 64 + mf * 16 + ln) * RSTB + swz;
    }

    int y0B  = l0 >> 6;         // B side row base (constant per block)
    int y0A0 = rbs >> 6;

    // issue stage (rt2,q2,h2): 12 async chunk loads
    auto issue = [&](int rt2, int q2, int h2) {
        int i2 = (q2 < 3) ? -1 : ((q2 < 6) ? 0 : 1);
        int j2 = q2 - (i2 + 1) * 3 - 1;
        int y0 = (w < 2) ? (y0A0 + rt2 * 2) : y0B;
        int su = (h2 * (4 * PAD_L) + (y0 + 1 + i2) * 66 + 1 + j2) * 16;
        #pragma unroll
        for (int n = 0; n < 12; ++n)
            gload16(bp + (su + LC[n]), (char*)LDSB + LB[n]);
    };

    // per-lane running max/argmax: one (m,a) per nf (this lane's 4 l-columns)
    float rm[4] = {-1e30f, -1e30f, -1e30f, -1e30f};
    int   ra[4] = {0, 0, 0, 0};

    issue(0, 0, 0);
    __syncthreads();            // vmcnt(0) drained before barrier

    for (int rt = 0; rt < NRT; ++rt) {
        int r0 = rbs + rt * BM;

        f32x4 acc[4][4];
        #pragma unroll
        for (int mf = 0; mf < 4; ++mf)
            #pragma unroll
            for (int nf = 0; nf < 4; ++nf)
                acc[mf][nf] = (f32x4){0.f, 0.f, 0.f, 0.f};

        for (int q = 0; q < 9; ++q) {
            for (int h = 0; h < 2; ++h) {
                // ---- read fragments of current stage ----
                short8b a[4][3], bb[4][3];
                const char* lc = (const char*)LDSB;
                #pragma unroll
                for (int mf = 0; mf < 4; ++mf)
                    #pragma unroll
                    for (int c = 0; c < 3; ++c) {
                        a[mf][c]  = *(const short8b*)(lc + arow[mf] + c * 64);
                        bb[mf][c] = *(const short8b*)(lc + brow[mf] + c * 64);
                    }
                __syncthreads();   // all waves' reads done

                // ---- issue next stage's async loads ----
                {
                    int h2 = h ^ 1, q2 = q, rt2 = rt;
                    if (h == 1) { q2 = q + 1; h2 = 0; if (q2 == 9) { q2 = 0; rt2 = rt + 1; } }
                    issue(rt2, q2, h2);
                }

                // ---- 6-product MFMA ----
                __builtin_amdgcn_s_setprio(1);
                #pragma unroll
                for (int mf = 0; mf < 4; ++mf)
                    #pragma unroll
                    for (int nf = 0; nf < 4; ++nf) {
                        f32x4 d = acc[mf][nf];
                        d = __builtin_amdgcn_mfma_f32_16x16x32_bf16(a[mf][0], bb[nf][0], d, 0, 0, 0);
                        d = __builtin_amdgcn_mfma_f32_16x16x32_bf16(a[mf][0], bb[nf][1], d, 0, 0, 0);
                        d = __builtin_amdgcn_mfma_f32_16x16x32_bf16(a[mf][1], bb[nf][0], d, 0, 0, 0);
                        d = __builtin_amdgcn_mfma_f32_16x16x32_bf16(a[mf][1], bb[nf][1], d, 0, 0, 0);
                        d = __builtin_amdgcn_mfma_f32_16x16x32_bf16(a[mf][0], bb[nf][2], d, 0, 0, 0);
                        d = __builtin_amdgcn_mfma_f32_16x16x32_bf16(a[mf][2], bb[nf][0], d, 0, 0, 0);
                        acc[mf][nf] = d;
                    }
                __builtin_amdgcn_s_setprio(0);
                __syncthreads();   // vmcnt(0): next stage landed in LDS
            }
        }

        // ---- register-only epilogue: scale, max/argmax, merge into running ----
        f32x4 inv4[4];
        #pragma unroll
        for (int mf = 0; mf < 4; ++mf)
            inv4[mf] = *(const f32x4*)&invn_rs[r0 + wr * 64 + mf * 16 + g * 4];
        #pragma unroll
        for (int nf = 0; nf < 4; ++nf) {
            float bv = -1e30f; int bi = 0;
            #pragma unroll
            for (int mf = 0; mf < 4; ++mf) {
                #pragma unroll
                for (int reg = 0; reg < 4; ++reg) {
                    int r = r0 + wr * 64 + mf * 16 + g * 4 + reg;
                    float val = acc[mf][nf][reg] * inv4[mf][reg];
                    if (val > bv || (val == bv && r < bi)) { bv = val; bi = r; }
                }
            }
            #pragma unroll
            for (int ofs = 16; ofs < 64; ofs <<= 1) {
                float ov = __shfl_xor(bv, ofs);
                int   oi = __shfl_xor(bi, ofs);
                if (ov > bv || (ov == bv && oi < bi)) { bv = ov; bi = oi; }
            }
            if (bv > rm[nf] || (bv == rm[nf] && bi < ra[nf])) { rm[nf] = bv; ra[nf] = bi; }
        }
    }

    // ---- final cross-wave merge (DMA quiescent: last barrier drained vmcnt) ----
    __syncthreads();
    float* sm2 = (float*)LDSB;            // [2][128]
    int*   si2 = (int*)LDSB + 256;        // [2][128]
    if (g == 0) {
        #pragma unroll
        for (int nf = 0; nf < 4; ++nf) {
            int col = wc * 64 + nf * 16 + ln;
            sm2[wr * 128 + col] = rm[nf];
            si2[wr * 128 + col] = ra[nf];
        }
    }
    __syncthreads();
    if (tid < 128) {
        float bm = sm2[tid]; int ba = si2[tid];
        float v  = sm2[128 + tid]; int a2 = si2[128 + tid];
        if (v > bm || (v == bm && a2 < ba)) { bm = v; ba = a2; }
        int l = l0 + tid;
        int o = (b * SPLITS + blockIdx.y) * LL + l;
        ws[WS_PMAX + o] = bm;
        ((int*)ws)[WS_PARG + o] = ba;
    }
}

// -------- 4) reduce over splits -> s output + final argmax --------
__global__ void k_reduce(float* __restrict__ ws, float* __restrict__ out) {
    int t = blockIdx.x * 256 + threadIdx.x;   // 0..B*L-1
    int b = t >> 12;
    int l = t & (LL - 1);
    float bm = -1e30f; int ba = 0;
    for (int s = 0; s < SPLITS; ++s) {        // splits are ascending r ranges
        int o = (b * SPLITS + s) * LL + l;
        float v = ws[WS_PMAX + o];
        int   a = ((int*)ws)[WS_PARG + o];
        if (v > bm || (v == bm && a < ba)) { bm = v; ba = a; }
    }
    out[t] = bm * ws[WS_INV_LR + t];          // s: [B,1,H,W] flat
    ((int*)ws)[WS_ARG + t] = ba;
}

// -------- 5) gather from ref via argmax + fold(3x3, pad 1) --------
__global__ void k_fold(const float* __restrict__ ref,
                       const float* __restrict__ ws,
                       float* __restrict__ out) {
    int t = blockIdx.x * 256 + threadIdx.x;   // 0..B*C*L-1
    int b = t >> 18;
    int c = (t >> 12) & 63;
    int yx = t & (LL - 1);
    int y = yx >> 6, x = yx & 63;
    const int* ab = ((const int*)ws) + WS_ARG + b * LL;
    const float* rb = ref + (size_t)b * CH * LL + c * LL;
    float s = 0.f;
    #pragma unroll
    for (int i = 0; i < 3; ++i) {
        int yp = y + 1 - i;
        if ((unsigned)yp >= (unsigned)HH) continue;
        #pragma unroll
        for (int j = 0; j < 3; ++j) {
            int xp = x + 1 - j;
            if ((unsigned)xp >= (unsigned)WW) continue;
            int r = ab[yp * WW + xp];
            int ry = (r >> 6) + i - 1;
            int rx = (r & 63) + j - 1;
            if ((unsigned)ry < (unsigned)HH && (unsigned)rx < (unsigned)WW)
                s += rb[ry * WW + rx];
        }
    }
    out[BATCH * LL + t] = s;                  // trans after s (16384 floats)
}

extern "C" void kernel_launch(void* const* d_in, const int* in_sizes, int n_in,
                              void* d_out, int out_size, void* d_ws, size_t ws_size,
                              hipStream_t stream) {
    const float* lrsr = (const float*)d_in[0];
    const float* refsr = (const float*)d_in[1];
    const float* ref  = (const float*)d_in[2];
    float* out = (float*)d_out;
    float* ws  = (float*)d_ws;

    // zero the padded pre-split region (borders must be 0)
    hipMemsetAsync((char*)d_ws + GP_BYTE_BASE, 0, GP_TOTAL, stream);
    k_split<<<dim3(16, 8, 8), dim3(256), 0, stream>>>(lrsr, refsr, ws);
    k_ssq<<<dim3(BATCH * LL / 256), dim3(256), 0, stream>>>(lrsr, refsr, ws);
    k_inv<<<dim3(BATCH * LL / 256), dim3(256), 0, stream>>>(ws);
    k_corrmax<<<dim3(LL / BN, SPLITS, BATCH), dim3(256), 0, stream>>>(ws);
    k_reduce<<<dim3(BATCH * LL / 256), dim3(256), 0, stream>>>(ws, out);
    k_fold<<<dim3(BATCH * CH * LL / 256), dim3(256), 0, stream>>>(ref, ws, out);
}

// Round 6
// 503.222 us; speedup vs baseline: 1.5742x; 1.5742x over previous
//
#include <hip/hip_runtime.h>

// Problem constants
#define BATCH 4
#define CH    64
#define HH    64
#define WW    64
#define LL    4096          // HH*WW
#define SPLITS 8
#define RPS   512           // LL/SPLITS
#define BM    128           // r tile
#define BN    128           // l tile
#define NRT   (RPS/BM)      // 4

// LDS tile: 13 slots of 16B per row (12 data = 3 comps x 32 k, 1 pad), 208 B/row
#define RSTB  208
#define NGR   3328          // granules per stage buffer: (128+128)*13
#define BUFB  53248         // bytes per stage buffer
#define BSOFF 26624         // B side byte offset within buffer (1664*16)

// Padded pre-split global image Gp[side][b][comp][c8(8)][4356][8ch] (ushort)
#define PAD_L   4356        // 66*66
#define GP_BYTE_BASE 1376256
#define GP_SIDE_STRIDE 6690816   // 4*3*8*4356*8*2
#define GP_B_STRIDE    1672704   // 3*8*4356*8*2
#define GP_COMP_STRIDE 557568    // 8*4356*16
#define GP_TOTAL       13381632  // 2*GP_SIDE_STRIDE
#define HOFF           278784    // h half-channel addend: 4*PAD_L*16

// Workspace layout (float words)
#define WS_SSQ_RS 0
#define WS_SSQ_LR 16384
#define WS_INV_RS 32768
#define WS_INV_LR 49152
#define WS_PMAX   65536      // [B*SPLITS*L] = 131072
#define WS_PARG   196608     // [B*SPLITS*L] = 131072
#define WS_ARG    327680     // [B*L]

typedef __attribute__((ext_vector_type(8))) short short8b;
typedef __attribute__((ext_vector_type(4))) float f32x4;
typedef __attribute__((ext_vector_type(16))) float f32x16;

__device__ __forceinline__ void gload16(const void* g, void* l) {
    __builtin_amdgcn_global_load_lds(
        (const __attribute__((address_space(1))) unsigned int*)g,
        (__attribute__((address_space(3))) unsigned int*)l, 16, 0, 0);
}

// -------- 0) pre-split: fp32 -> 3 truncated bf16 comps, padded image --------
__global__ void k_split(const float* __restrict__ lrsr,
                        const float* __restrict__ refsr,
                        float* __restrict__ ws) {
    int tid  = threadIdx.x;
    int pos  = blockIdx.x * 256 + tid;          // 0..4095
    int c8   = blockIdx.y;                      // 0..7
    int side = blockIdx.z >> 2;                 // 0 = refsr(A), 1 = lrsr(B)
    int b    = blockIdx.z & 3;
    const float* src = (side ? lrsr : refsr) + (size_t)b * CH * LL + c8 * 8 * LL + pos;
    int ppos = (pos >> 6) * 66 + (pos & 63) + 67;   // (y+1)*66 + (x+1)
    char* dst = (char*)ws + GP_BYTE_BASE + side * GP_SIDE_STRIDE + b * GP_B_STRIDE
              + (size_t)(c8 * PAD_L + ppos) * 16;
    union { unsigned short u[8]; uint4 v; } w0, w1, w2;
    #pragma unroll
    for (int cc = 0; cc < 8; ++cc) {
        float x = src[cc * LL];
        unsigned u0 = __float_as_uint(x);
        float f0 = __uint_as_float(u0 & 0xffff0000u);
        float r1 = x - f0;
        unsigned u1 = __float_as_uint(r1);
        float f1 = __uint_as_float(u1 & 0xffff0000u);
        float r2 = r1 - f1;
        w0.u[cc] = (unsigned short)(u0 >> 16);
        w1.u[cc] = (unsigned short)(u1 >> 16);
        w2.u[cc] = (unsigned short)(__float_as_uint(r2) >> 16);
    }
    *(uint4*)(dst)                      = w0.v;
    *(uint4*)(dst + GP_COMP_STRIDE)     = w1.v;
    *(uint4*)(dst + 2 * GP_COMP_STRIDE) = w2.v;
}

// -------- 1) channel sum-of-squares per position (both inputs) --------
__global__ void k_ssq(const float* __restrict__ lrsr,
                      const float* __restrict__ refsr,
                      float* __restrict__ ws) {
    int t = blockIdx.x * 256 + threadIdx.x;      // 0..B*L-1
    int b = t >> 12;
    int r = t & (LL - 1);
    const float* pl = lrsr + (size_t)b * CH * LL + r;
    const float* pr = refsr + (size_t)b * CH * LL + r;
    float sl = 0.f, sr = 0.f;
    #pragma unroll 8
    for (int c = 0; c < CH; ++c) {
        float a = pl[c * LL]; sl += a * a;
        float d = pr[c * LL]; sr += d * d;
    }
    ws[WS_SSQ_RS + t] = sr;
    ws[WS_SSQ_LR + t] = sl;
}

// -------- 2) 3x3 box-sum of ssq (zero pad) -> 1/max(norm,eps) --------
__global__ void k_inv(float* __restrict__ ws) {
    int t = blockIdx.x * 256 + threadIdx.x;      // 0..B*L-1
    int b = t >> 12;
    int r = t & (LL - 1);
    int y = r >> 6, x = r & 63;
    float srs = 0.f, slr = 0.f;
    for (int di = -1; di <= 1; ++di) {
        int yy = y + di;
        if ((unsigned)yy >= (unsigned)HH) continue;
        for (int dj = -1; dj <= 1; ++dj) {
            int xx = x + dj;
            if ((unsigned)xx >= (unsigned)WW) continue;
            int idx = b * LL + yy * WW + xx;
            srs += ws[WS_SSQ_RS + idx];
            slr += ws[WS_SSQ_LR + idx];
        }
    }
    ws[WS_INV_RS + t] = 1.f / fmaxf(sqrtf(srs), 1e-12f);
    ws[WS_INV_LR + t] = 1.f / fmaxf(sqrtf(slr), 1e-12f);
}

// -------- 3) MFMA corr GEMM: 32x32x16, dbuf LDS, 1 barrier/stage --------
__global__ __launch_bounds__(512, 2)
void k_corrmax(float* __restrict__ ws) {
    __shared__ __align__(16) char LDSB[2 * BUFB];   // 104 KB double buffer

    int tid  = threadIdx.x;
    int b    = blockIdx.z;
    int bx   = blockIdx.x;
    int l0   = bx * BN;
    int rbs  = blockIdx.y * RPS;

    int lane = tid & 63;
    int w    = tid >> 6;        // wave 0..7
    int wr   = w >> 2;          // r half 0..1 (64 rows each)
    int wc   = w & 3;           // l quarter 0..3 (32 cols each)
    int l31  = lane & 31;
    int g2   = lane >> 5;       // k-octet selector

    const float* invn_rs = ws + WS_INV_RS + b * LL;
    const char*  gpB = (const char*)ws + GP_BYTE_BASE + b * GP_B_STRIDE;

    // ---- per-lane staging constants: up to 7 chunk-issues per wave ----
    // granule G in [0,3328): side A = [0,1664), B = [1664,3328)
    int LCb[7];
    int sideF[7];
    #pragma unroll
    for (int n = 0; n < 7; ++n) {
        int cid = n * 8 + w;
        if (cid < 52) {
            int G    = cid * 64 + lane;
            int side = (G >= 1664) ? 1 : 0;
            int gg   = G - side * 1664;
            int row  = gg / 13;
            int slot = gg - row * 13;
            int base = side * GP_SIDE_STRIDE + (row + 2 * (row >> 6)) * 16;
            if (slot < 12)
                base += (slot >> 2) * GP_COMP_STRIDE + (slot & 3) * (PAD_L * 16);
            LCb[n]   = base;
            sideF[n] = side;
        } else { LCb[n] = 0; sideF[n] = 0; }
    }

    // ---- fragment LDS byte offsets (ks adds +32, comp c at +c*64) ----
    int aoff[2][3], boff[3];
    #pragma unroll
    for (int mf = 0; mf < 2; ++mf)
        #pragma unroll
        for (int c = 0; c < 3; ++c)
            aoff[mf][c] = (wr * 64 + mf * 32 + l31) * RSTB + c * 64 + g2 * 16;
    #pragma unroll
    for (int c = 0; c < 3; ++c)
        boff[c] = BSOFF + (wc * 32 + l31) * RSTB + c * 64 + g2 * 16;

    int yb = rbs >> 6;          // A-side y base (blockIdx.y * 8)
    int yB = bx * 2;            // B-side y base

    auto issue = [&](int rt2, int q2, int h2, int bufo) {
        int i2 = (q2 < 3) ? -1 : ((q2 < 6) ? 0 : 1);
        int j2 = q2 - (i2 + 1) * 3 - 1;
        int suA = ((yb + rt2 * 2 + 1 + i2) * 66 + 1 + j2) * 16 + h2 * HOFF;
        int suB = ((yB + 1 + i2) * 66 + 1 + j2) * 16 + h2 * HOFF;
        #pragma unroll
        for (int n = 0; n < 7; ++n) {
            int cid = n * 8 + w;
            if (cid < 52) {        // wave-uniform condition
                int su = sideF[n] ? suB : suA;
                gload16(gpB + (LCb[n] + su), LDSB + bufo + cid * 1024);
            }
        }
    };

    float rm = -1e30f;          // running max for this lane's l column
    int   ra = 0;

    issue(0, 0, 0, 0);
    __syncthreads();            // vmcnt(0) drained

    int cur = 0;
    for (int rt = 0; rt < NRT; ++rt) {
        int r0 = rbs + rt * BM;

        f32x16 acc[2];
        #pragma unroll
        for (int mf = 0; mf < 2; ++mf)
            #pragma unroll
            for (int e = 0; e < 16; ++e) acc[mf][e] = 0.f;

        for (int q = 0; q < 9; ++q) {
            for (int h = 0; h < 2; ++h) {
                // ---- prefetch next stage into the other buffer ----
                if (!(rt == NRT - 1 && q == 8 && h == 1)) {
                    int h2 = h ^ 1, q2 = q, rt2 = rt;
                    if (h == 1) { q2 = q + 1; h2 = 0; if (q2 == 9) { q2 = 0; rt2 = (rt + 1) & (NRT - 1); } }
                    issue(rt2, q2, h2, (cur ^ 1) * BUFB);
                }
                // ---- fragments + MFMA from current buffer ----
                const char* lb = LDSB + cur * BUFB;
                #pragma unroll
                for (int ks = 0; ks < 2; ++ks) {
                    short8b a[2][3], bv[3];
                    #pragma unroll
                    for (int mf = 0; mf < 2; ++mf)
                        #pragma unroll
                        for (int c = 0; c < 3; ++c)
                            a[mf][c] = *(const short8b*)(lb + aoff[mf][c] + ks * 32);
                    #pragma unroll
                    for (int c = 0; c < 3; ++c)
                        bv[c] = *(const short8b*)(lb + boff[c] + ks * 32);
                    __builtin_amdgcn_s_setprio(1);
                    #pragma unroll
                    for (int mf = 0; mf < 2; ++mf) {
                        f32x16 d = acc[mf];
                        d = __builtin_amdgcn_mfma_f32_32x32x16_bf16(a[mf][0], bv[0], d, 0, 0, 0);
                        d = __builtin_amdgcn_mfma_f32_32x32x16_bf16(a[mf][0], bv[1], d, 0, 0, 0);
                        d = __builtin_amdgcn_mfma_f32_32x32x16_bf16(a[mf][1], bv[0], d, 0, 0, 0);
                        d = __builtin_amdgcn_mfma_f32_32x32x16_bf16(a[mf][1], bv[1], d, 0, 0, 0);
                        d = __builtin_amdgcn_mfma_f32_32x32x16_bf16(a[mf][0], bv[2], d, 0, 0, 0);
                        d = __builtin_amdgcn_mfma_f32_32x32x16_bf16(a[mf][2], bv[0], d, 0, 0, 0);
                        acc[mf] = d;
                    }
                    __builtin_amdgcn_s_setprio(0);
                }
                __syncthreads();   // drains vmcnt (prefetch landed) + all LDS reads done
                cur ^= 1;
            }
        }

        // ---- epilogue: scale by invn_rs, merge into running (m,a) ----
        // C layout: col = lane&31, row = (reg&3) + 8*(reg>>2) + 4*(lane>>5)
        f32x4 inv4[2][4];
        #pragma unroll
        for (int mf = 0; mf < 2; ++mf)
            #pragma unroll
            for (int rb = 0; rb < 4; ++rb)
                inv4[mf][rb] = *(const f32x4*)&invn_rs[r0 + wr * 64 + mf * 32 + g2 * 4 + rb * 8];
        #pragma unroll
        for (int mf = 0; mf < 2; ++mf)
            #pragma unroll
            for (int reg = 0; reg < 16; ++reg) {
                int r = r0 + wr * 64 + mf * 32 + (reg & 3) + 8 * (reg >> 2) + 4 * g2;
                float val = acc[mf][reg] * inv4[mf][reg >> 2][reg & 3];
                if (val > rm || (val == rm && r < ra)) { rm = val; ra = r; }
            }
    }

    // ---- lane-pair merge (lanes l, l+32 hold same column) ----
    {
        float ov = __shfl_xor(rm, 32);
        int   oi = __shfl_xor(ra, 32);
        if (ov > rm || (ov == rm && oi < ra)) { rm = ov; ra = oi; }
    }
    // ---- cross-wave merge over wr halves (LDS quiescent after last barrier) ----
    __syncthreads();
    float* sm2 = (float*)LDSB;          // [2][128]
    int*   si2 = (int*)LDSB + 256;      // [2][128]
    if (lane < 32) {
        sm2[wr * 128 + wc * 32 + l31] = rm;
        si2[wr * 128 + wc * 32 + l31] = ra;
    }
    __syncthreads();
    if (tid < 128) {
        float bm = sm2[tid]; int ba = si2[tid];
        float v  = sm2[128 + tid]; int a2 = si2[128 + tid];
        if (v > bm || (v == bm && a2 < ba)) { bm = v; ba = a2; }
        int l = l0 + tid;
        int o = (b * SPLITS + blockIdx.y) * LL + l;
        ws[WS_PMAX + o] = bm;
        ((int*)ws)[WS_PARG + o] = ba;
    }
}

// -------- 4) reduce over splits -> s output + final argmax --------
__global__ void k_reduce(float* __restrict__ ws, float* __restrict__ out) {
    int t = blockIdx.x * 256 + threadIdx.x;   // 0..B*L-1
    int b = t >> 12;
    int l = t & (LL - 1);
    float bm = -1e30f; int ba = 0;
    for (int s = 0; s < SPLITS; ++s) {        // splits are ascending r ranges
        int o = (b * SPLITS + s) * LL + l;
        float v = ws[WS_PMAX + o];
        int   a = ((int*)ws)[WS_PARG + o];
        if (v > bm || (v == bm && a < ba)) { bm = v; ba = a; }
    }
    out[t] = bm * ws[WS_INV_LR + t];          // s: [B,1,H,W] flat
    ((int*)ws)[WS_ARG + t] = ba;
}

// -------- 5) gather from ref via argmax + fold(3x3, pad 1) --------
__global__ void k_fold(const float* __restrict__ ref,
                       const float* __restrict__ ws,
                       float* __restrict__ out) {
    int t = blockIdx.x * 256 + threadIdx.x;   // 0..B*C*L-1
    int b = t >> 18;
    int c = (t >> 12) & 63;
    int yx = t & (LL - 1);
    int y = yx >> 6, x = yx & 63;
    const int* ab = ((const int*)ws) + WS_ARG + b * LL;
    const float* rb = ref + (size_t)b * CH * LL + c * LL;
    float s = 0.f;
    #pragma unroll
    for (int i = 0; i < 3; ++i) {
        int yp = y + 1 - i;
        if ((unsigned)yp >= (unsigned)HH) continue;
        #pragma unroll
        for (int j = 0; j < 3; ++j) {
            int xp = x + 1 - j;
            if ((unsigned)xp >= (unsigned)WW) continue;
            int r = ab[yp * WW + xp];
            int ry = (r >> 6) + i - 1;
            int rx = (r & 63) + j - 1;
            if ((unsigned)ry < (unsigned)HH && (unsigned)rx < (unsigned)WW)
                s += rb[ry * WW + rx];
        }
    }
    out[BATCH * LL + t] = s;                  // trans after s (16384 floats)
}

extern "C" void kernel_launch(void* const* d_in, const int* in_sizes, int n_in,
                              void* d_out, int out_size, void* d_ws, size_t ws_size,
                              hipStream_t stream) {
    const float* lrsr = (const float*)d_in[0];
    const float* refsr = (const float*)d_in[1];
    const float* ref  = (const float*)d_in[2];
    float* out = (float*)d_out;
    float* ws  = (float*)d_ws;

    // zero the padded pre-split region (borders must be 0)
    hipMemsetAsync((char*)d_ws + GP_BYTE_BASE, 0, GP_TOTAL, stream);
    k_split<<<dim3(16, 8, 8), dim3(256), 0, stream>>>(lrsr, refsr, ws);
    k_ssq<<<dim3(BATCH * LL / 256), dim3(256), 0, stream>>>(lrsr, refsr, ws);
    k_inv<<<dim3(BATCH * LL / 256), dim3(256), 0, stream>>>(ws);
    k_corrmax<<<dim3(LL / BN, SPLITS, BATCH), dim3(512), 0, stream>>>(ws);
    k_reduce<<<dim3(BATCH * LL / 256), dim3(256), 0, stream>>>(ws, out);
    k_fold<<<dim3(BATCH * CH * LL / 256), dim3(256), 0, stream>>>(ref, ws, out);
}